// Round 11
// baseline (136.567 us; speedup 1.0000x reference)
//
#include <hip/hip_runtime.h>
#include <hip/hip_cooperative_groups.h>
#include <math.h>

namespace cg = cooperative_groups;

#define B 8
#define G 64
#define S 256
#define DIM 41
#define ET 128
#define H 8
#define EK 16
#define NH 127
#define HD (H*DIM)   // 328
#define EROW 257     // padded e-row

// ---------------- single cooperative kernel: 512 blocks x 512 threads ----------------
// Phase A (block-striped prep): kproj 4 rows, qproj 1 row (4-way split-K), embits 1 bg.
// grid.sync()
// Phase B (block = bg): scores + softmax + weighted + outproj (all proven code).
__global__ __launch_bounds__(512, 4) void mono_kernel(const float* __restrict__ query,
                                                      const float* __restrict__ key,
                                                      const float* __restrict__ value,
                                                      const float* __restrict__ mask,
                                                      const float* __restrict__ qt,
                                                      const float* __restrict__ tt,
                                                      const float* __restrict__ stride_in,
                                                      const float* __restrict__ Wq,
                                                      const float* __restrict__ bq,
                                                      const float* __restrict__ Wk,
                                                      const float* __restrict__ bk,
                                                      const float* __restrict__ Wo,
                                                      const float* __restrict__ bo,
                                                      const float* __restrict__ Wr,
                                                      const float* __restrict__ br,
                                                      float* __restrict__ kpT,
                                                      float* __restrict__ qp,
                                                      unsigned int* __restrict__ embitsT,
                                                      float* __restrict__ out) {
    __shared__ float smem[5312];        // 21.2 KB, aliased across phases
    const int bid = blockIdx.x;
    const int tid = threadIdx.x;

    // ================= Phase A =================
    // ---- A1: kproj rows bid*4 .. bid*4+3 -> kpT float layout b*32768 + (j>>2)*1024 + s*4 + (j&3)
    {
        float* klds = smem;             // [4][48]
        const int quarter = tid >> 7;
        const int j = tid & 127;
        const int row = bid * 4 + quarter;   // 512*4 = 2048 rows
        if (j < DIM) klds[quarter * 48 + j] = key[row * DIM + j];
        __syncthreads();
        const float* kr = klds + quarter * 48;
        float acc = bk[j];
#pragma unroll
        for (int i = 0; i < DIM; ++i) acc = fmaf(kr[i], Wk[i * ET + j], acc);
        const int b = row >> 8, s = row & 255;
        kpT[b * 32768 + (j >> 2) * 1024 + s * 4 + (j & 3)] = acc;
        __syncthreads();
    }
    // ---- A2: qproj row bid, 4-way split-K
    {
        float* qlds = smem;             // [128]
        float* part = smem + 128;       // [4][128]
        if (tid < ET) qlds[tid] = query[(size_t)bid * ET + tid];
        __syncthreads();
        const int j = tid & 127, c = tid >> 7;
        float a = 0.f;
        const int i0 = c * 32;
#pragma unroll 8
        for (int i = i0; i < i0 + 32; ++i) a = fmaf(qlds[i], Wq[i * ET + j], a);
        part[c * 128 + j] = a;
        __syncthreads();
        if (tid < ET)
            qp[(size_t)bid * ET + tid] = bq[tid] + ((part[tid] + part[128 + tid]) +
                                                    (part[256 + tid] + part[384 + tid]));
        __syncthreads();
    }
    // ---- A3: embits for bg = bid (proven r3 code, staging loop stride 512)
    {
        float* mlds = smem;
        float* strd = smem + 5248;
        const int bg = bid;
        const int b = bg >> 6, g = bg & 63;
        if (tid < DIM) {
            float a = br[tid];
            for (int i = 0; i < DIM; ++i) a = fmaf(stride_in[i], Wr[i * DIM + tid], a);
            strd[tid] = 1.0f / (1.0f + expf(-a));
        }
        __syncthreads();
        const float qtg = qt[g];
        for (int rr = 0; rr < 2; ++rr) {
            for (int idx = tid; idx < 5248; idx += 512)
                mlds[idx] = mask[(size_t)b * S * DIM + rr * 5248 + idx];
            __syncthreads();
            if (tid < 128) {
                const int s = rr * 128 + tid;
                const float t = tt[b * S + s];
                const int wv = tid >> 6;
                const int w = rr * 2 + wv;
                unsigned int* op = embitsT + (size_t)bg * (DIM * 8) + w * 2;
#pragma unroll
                for (int d = 0; d < DIM; ++d) {
                    const float sd = strd[d];
                    const int ok = (t >= qtg - sd) & (t <= qtg + sd) & (mlds[tid * DIM + d] != 0.0f);
                    const unsigned long long bal = __ballot(ok);
                    if ((tid & 63) == 0) {
                        op[d * 8 + 0] = (unsigned int)bal;
                        op[d * 8 + 1] = (unsigned int)(bal >> 32);
                    }
                }
            }
            __syncthreads();
        }
    }

    __threadfence();
    cg::this_grid().sync();

    // ================= Phase B: bg = bid =================
    float* se   = smem;                 // [H][257] = 2056
    float* qv   = smem + 2056;          // [128]
    float* Mb   = smem + 2184;          // [8]
    float* xrow = smem + 2192;          // [328]
    float* po   = smem + 2520;          // [4][128]

    const int bg = bid;
    const int b = bg >> 6;

    if (tid < ET) qv[tid] = qp[(size_t)bg * ET + tid];
    __syncthreads();

    // scores: thread = s (256 of 512), 8 heads in registers (proven r3)
    float sc8[H];
    if (tid < S) {
        const float4* kb = reinterpret_cast<const float4*>(kpT) + (size_t)b * 8192 + tid;
#pragma unroll
        for (int h = 0; h < H; ++h) {
            float a = 0.f;
#pragma unroll
            for (int e4 = 0; e4 < 4; ++e4) {
                const float4 kv = kb[(h * 4 + e4) * 256];
                a = fmaf(qv[h * EK + e4 * 4 + 0], kv.x, a);
                a = fmaf(qv[h * EK + e4 * 4 + 1], kv.y, a);
                a = fmaf(qv[h * EK + e4 * 4 + 2], kv.z, a);
                a = fmaf(qv[h * EK + e4 * 4 + 3], kv.w, a);
            }
            sc8[h] = a * 0.25f;          // 1/sqrt(EK)
            se[h * EROW + tid] = sc8[h];
        }
    }
    __syncthreads();

    // per-head max (proven)
    if (tid < S) {
        const int h = tid >> 5, j = tid & 31;
        float m = se[h * EROW + j];
#pragma unroll
        for (int k = 1; k < 8; ++k) m = fmaxf(m, se[h * EROW + j + 32 * k]);
#pragma unroll
        for (int off = 16; off; off >>= 1) m = fmaxf(m, __shfl_xor(m, off, 32));
        if (j == 0) Mb[h] = m;
    }
    __syncthreads();

    // exp (from registers)
    if (tid < S) {
#pragma unroll
        for (int h = 0; h < H; ++h) se[h * EROW + tid] = __expf(sc8[h] - Mb[h]);
    }
    __syncthreads();

    // weighted phase (proven r8): wave = head, lane = d; value from global (L2-hot)
    {
        const int w = tid >> 6;          // head 0..7
        const int d = tid & 63;
        if (d < DIM) {
            const uint4* bp = reinterpret_cast<const uint4*>(embitsT + (size_t)bg * (DIM * 8) + d * 8);
            const uint4 b0 = bp[0], b1 = bp[1];
            const unsigned int bw[8] = {b0.x, b0.y, b0.z, b0.w, b1.x, b1.y, b1.z, b1.w};
            const float* er = &se[w * EROW];
            const float* vb = value + (size_t)b * S * DIM + d;
            float Ssum = 0.f, acc = 0.f;
#pragma unroll
            for (int k = 0; k < 8; ++k) {
                const unsigned int wv = bw[k];
#pragma unroll 8
                for (int i = 0; i < 32; ++i) {
                    const int s = k * 32 + i;
                    const float e = er[s];
                    const float v = vb[(size_t)s * DIM];
                    const float wgt = ((wv >> i) & 1u) ? e : 0.f;
                    Ssum += wgt;
                    acc = fmaf(wgt, v, acc);
                }
            }
            float r;
            if (Ssum != 0.f) {
                r = acc / Ssum;
            } else {
                // all-masked column: uniform softmax -> column mean (never taken in practice)
                float vs = 0.f;
                for (int s2 = 0; s2 < S; ++s2) vs += vb[(size_t)s2 * DIM];
                r = vs * (1.0f / S);
            }
            xrow[w * DIM + d] = r;
        }
    }
    __syncthreads();

    // out-proj (proven r4): 4 i-chunks of 82, lanes n = tid&127
    {
        const int n = tid & 127, c = tid >> 7;
        if (n < NH) {
            const int i0 = c * 82;
            float a0 = 0.f, a1 = 0.f;
#pragma unroll 2
            for (int i = i0; i < i0 + 82; i += 2) {
                a0 = fmaf(xrow[i],     Wo[(size_t)i * NH + n],       a0);
                a1 = fmaf(xrow[i + 1], Wo[(size_t)(i + 1) * NH + n], a1);
            }
            po[c * 128 + n] = a0 + a1;
        }
    }
    __syncthreads();
    if (tid < NH)
        out[(size_t)bg * NH + tid] = bo[tid] + ((po[tid] + po[128 + tid]) +
                                                (po[256 + tid] + po[384 + tid]));
}

extern "C" void kernel_launch(void* const* d_in, const int* in_sizes, int n_in,
                              void* d_out, int out_size, void* d_ws, size_t ws_size,
                              hipStream_t stream) {
    const float* query     = (const float*)d_in[0];
    const float* key       = (const float*)d_in[1];
    const float* value     = (const float*)d_in[2];
    const float* mask      = (const float*)d_in[3];
    const float* qt        = (const float*)d_in[4];
    const float* tt        = (const float*)d_in[5];
    const float* stride_in = (const float*)d_in[6];
    const float* Wq        = (const float*)d_in[7];
    const float* bq        = (const float*)d_in[8];
    const float* Wk        = (const float*)d_in[9];
    const float* bk        = (const float*)d_in[10];
    const float* Wo        = (const float*)d_in[11];
    const float* bo        = (const float*)d_in[12];
    const float* Wr        = (const float*)d_in[13];
    const float* br        = (const float*)d_in[14];
    float* out = (float*)d_out;

    float* kpT = (float*)d_ws;                                         // 262144 f32
    float* qp = kpT + (size_t)B * H * 4 * S * 4;                       // 65536 f32
    unsigned int* embitsT = (unsigned int*)(qp + (size_t)B * G * ET);  // B*G*DIM*8 u32

    void* args[] = {
        (void*)&query, (void*)&key, (void*)&value, (void*)&mask,
        (void*)&qt, (void*)&tt, (void*)&stride_in,
        (void*)&Wq, (void*)&bq, (void*)&Wk, (void*)&bk,
        (void*)&Wo, (void*)&bo, (void*)&Wr, (void*)&br,
        (void*)&kpT, (void*)&qp, (void*)&embitsT, (void*)&out
    };
    hipLaunchCooperativeKernel(reinterpret_cast<const void*>(mono_kernel),
                               dim3(512), dim3(512), args, 0, stream);
}